// Round 1
// baseline (255.493 us; speedup 1.0000x reference)
//
#include <hip/hip_runtime.h>
#include <hip/hip_bf16.h>
#include <stdint.h>

#define N 8192
#define D 512
#define TILE 128
#define BK 64

typedef __attribute__((ext_vector_type(8))) short bf16x8;
typedef __attribute__((ext_vector_type(4))) float f32x4;

// async global->LDS, 16B per lane; LDS dest = wave-uniform base + lane*16
__device__ __forceinline__ void gload_lds16(const void* gp, const void* lp) {
    auto g = (const __attribute__((address_space(1))) void*)(uintptr_t)gp;
    auto l = (__attribute__((address_space(3))) void*)(uintptr_t)lp;
    __builtin_amdgcn_global_load_lds(g, l, 16, 0, 0);
}

__device__ __forceinline__ short f2bf(float x) {
    uint32_t u = __float_as_uint(x);
    u += 0x7fffu + ((u >> 16) & 1u);   // RNE; inputs are finite/small
    return (short)(u >> 16);
}

// one wave per row: fp32 row -> L2-normalized bf16 row
__global__ void cc_normalize(const float* __restrict__ F, short* __restrict__ Fn) {
    const int row  = blockIdx.x * 4 + (threadIdx.x >> 6);
    const int lane = threadIdx.x & 63;
    const float4* src = (const float4*)(F + (size_t)row * D);
    float4 a = src[lane];
    float4 b = src[lane + 64];
    float ss = a.x*a.x + a.y*a.y + a.z*a.z + a.w*a.w
             + b.x*b.x + b.y*b.y + b.z*b.z + b.w*b.w;
    #pragma unroll
    for (int m = 32; m; m >>= 1) ss += __shfl_xor(ss, m, 64);
    const float inv = 1.0f / fmaxf(sqrtf(ss), 1e-12f);
    short4 o0 = make_short4(f2bf(a.x*inv), f2bf(a.y*inv), f2bf(a.z*inv), f2bf(a.w*inv));
    short4 o1 = make_short4(f2bf(b.x*inv), f2bf(b.y*inv), f2bf(b.z*inv), f2bf(b.w*inv));
    *(short4*)(Fn + (size_t)row * D + lane * 4)       = o0;
    *(short4*)(Fn + (size_t)row * D + 256 + lane * 4) = o1;
}

// fused C = Fn*Fn^T tile -> exp -> masked row sums -> atomics into tot/pos
__global__ void cc_gemm(const short* __restrict__ Fn, const int* __restrict__ cl,
                        float* __restrict__ tot, float* __restrict__ pos) {
    __shared__ __align__(16) short As[TILE * BK];   // [row][k] 128x64 bf16
    __shared__ __align__(16) short Bs[TILE * BK];
    __shared__ int crow[TILE], ccol[TILE];

    const int tid  = threadIdx.x;
    const int wave = tid >> 6;
    const int lane = tid & 63;
    const int bm = blockIdx.y, bn = blockIdx.x;

    if (tid < TILE)            crow[tid]        = cl[bm * TILE + tid];
    else                       ccol[tid - TILE] = cl[bn * TILE + (tid - TILE)];

    const int wr = wave >> 1, wc = wave & 1;    // 2x2 wave grid, 64x64 each

    f32x4 acc[4][4];
    #pragma unroll
    for (int t = 0; t < 4; ++t)
        #pragma unroll
        for (int u = 0; u < 4; ++u) acc[t][u] = (f32x4)(0.0f);

    const int lrow = lane >> 3;          // 0..7   (row within 8-row chunk)
    const int lcol = (lane & 7) * 8;     // bf16 col offset, 16B per lane

    for (int kc = 0; kc < D / BK; ++kc) {
        __syncthreads();                 // LDS free (also covers crow/ccol on kc=0)
        #pragma unroll
        for (int i = 0; i < 4; ++i) {
            const int rb = i * 32 + wave * 8;            // wave-uniform row base
            const short* ga = Fn + (size_t)(bm * TILE + rb + lrow) * D + kc * BK + lcol;
            gload_lds16(ga, &As[rb * BK]);
            const short* gb = Fn + (size_t)(bn * TILE + rb + lrow) * D + kc * BK + lcol;
            gload_lds16(gb, &Bs[rb * BK]);
        }
        __syncthreads();                 // compiler drains vmcnt before barrier
        #pragma unroll
        for (int ks = 0; ks < 2; ++ks) {
            const int ko = ks * 32 + (lane >> 4) * 8;    // k = quad*8 + j
            bf16x8 af[4], bfr[4];
            #pragma unroll
            for (int t = 0; t < 4; ++t)
                af[t] = *(const bf16x8*)&As[(wr * 64 + t * 16 + (lane & 15)) * BK + ko];
            #pragma unroll
            for (int u = 0; u < 4; ++u)
                bfr[u] = *(const bf16x8*)&Bs[(wc * 64 + u * 16 + (lane & 15)) * BK + ko];
            #pragma unroll
            for (int t = 0; t < 4; ++t)
                #pragma unroll
                for (int u = 0; u < 4; ++u)
                    acc[t][u] = __builtin_amdgcn_mfma_f32_16x16x32_bf16(af[t], bfr[u], acc[t][u], 0, 0, 0);
        }
    }

    // epilogue: e = exp(sim/T) = exp2(dot * 10*log2(e)); C layout col=lane&15,row=quad*4+reg
    const float SC = 14.426950408889634f;
    const int q   = lane >> 4;
    const int n15 = lane & 15;
    int cc[4];
    #pragma unroll
    for (int u = 0; u < 4; ++u) cc[u] = ccol[wc * 64 + u * 16 + n15];

    #pragma unroll
    for (int t = 0; t < 4; ++t) {
        #pragma unroll
        for (int r = 0; r < 4; ++r) {
            const int lr  = wr * 64 + t * 16 + q * 4 + r;   // local row
            const int myc = crow[lr];
            float te = 0.0f, tp = 0.0f;
            #pragma unroll
            for (int u = 0; u < 4; ++u) {
                const float e = exp2f(acc[t][u][r] * SC);
                te += e;
                tp += (cc[u] == myc) ? e : 0.0f;
            }
            #pragma unroll
            for (int m = 1; m < 16; m <<= 1) {   // reduce across 16 cols
                te += __shfl_xor(te, m, 64);
                tp += __shfl_xor(tp, m, 64);
            }
            if (n15 == 0) {
                const int grow = bm * TILE + lr;
                atomicAdd(&tot[grow], te);
                atomicAdd(&pos[grow], tp);
            }
        }
    }
}

// single block: loss_i = log(tot+1e-8) - log(pos); out = sum
__global__ void cc_finalize(const float* __restrict__ tot, const float* __restrict__ pos,
                            float* __restrict__ out) {
    __shared__ float red[4];
    float s = 0.0f;
    for (int i = threadIdx.x; i < N; i += 256)
        s += logf(tot[i] + 1e-8f) - logf(pos[i]);
    #pragma unroll
    for (int m = 32; m; m >>= 1) s += __shfl_xor(s, m, 64);
    const int wave = threadIdx.x >> 6, lane = threadIdx.x & 63;
    if (lane == 0) red[wave] = s;
    __syncthreads();
    if (threadIdx.x == 0) out[0] = red[0] + red[1] + red[2] + red[3];
}

extern "C" void kernel_launch(void* const* d_in, const int* in_sizes, int n_in,
                              void* d_out, int out_size, void* d_ws, size_t ws_size,
                              hipStream_t stream) {
    const float* F  = (const float*)d_in[0];
    const int*   cl = (const int*)d_in[1];
    float* out = (float*)d_out;

    short* Fn  = (short*)d_ws;                                   // 8192*512 bf16 = 8 MB
    float* tot = (float*)((char*)d_ws + (size_t)N * D * 2);      // 32 KB
    float* pos = tot + N;                                        // 32 KB

    hipMemsetAsync(tot, 0, 2 * N * sizeof(float), stream);
    cc_normalize<<<N / 4, 256, 0, stream>>>(F, Fn);
    dim3 grid(N / TILE, N / TILE);
    cc_gemm<<<grid, 256, 0, stream>>>(Fn, cl, tot, pos);
    cc_finalize<<<1, 256, 0, stream>>>(tot, pos, out);
}

// Round 2
// 182.708 us; speedup vs baseline: 1.3984x; 1.3984x over previous
//
#include <hip/hip_runtime.h>
#include <hip/hip_bf16.h>
#include <stdint.h>

#define N 8192
#define D 512
#define TILE 128
#define BK 64
#define NTB (N / TILE)   // 64 tile-rows; upper-tri blocks = 64*65/2 = 2080

typedef __attribute__((ext_vector_type(8))) short bf16x8;
typedef __attribute__((ext_vector_type(4))) float f32x4;

// async global->LDS, 16B per lane; LDS dest = wave-uniform base + lane*16
__device__ __forceinline__ void gload_lds16(const void* gp, const void* lp) {
    auto g = (const __attribute__((address_space(1))) void*)(uintptr_t)gp;
    auto l = (__attribute__((address_space(3))) void*)(uintptr_t)lp;
    __builtin_amdgcn_global_load_lds(g, l, 16, 0, 0);
}

__device__ __forceinline__ short f2bf(float x) {
    uint32_t u = __float_as_uint(x);
    u += 0x7fffu + ((u >> 16) & 1u);   // RNE; inputs are finite/small
    return (short)(u >> 16);
}

// one wave per row: fp32 row -> L2-normalized bf16 row
__global__ void cc_normalize(const float* __restrict__ F, short* __restrict__ Fn) {
    const int row  = blockIdx.x * 4 + (threadIdx.x >> 6);
    const int lane = threadIdx.x & 63;
    const float4* src = (const float4*)(F + (size_t)row * D);
    float4 a = src[lane];
    float4 b = src[lane + 64];
    float ss = a.x*a.x + a.y*a.y + a.z*a.z + a.w*a.w
             + b.x*b.x + b.y*b.y + b.z*b.z + b.w*b.w;
    #pragma unroll
    for (int m = 32; m; m >>= 1) ss += __shfl_xor(ss, m, 64);
    const float inv = 1.0f / fmaxf(sqrtf(ss), 1e-12f);
    short4 o0 = make_short4(f2bf(a.x*inv), f2bf(a.y*inv), f2bf(a.z*inv), f2bf(a.w*inv));
    short4 o1 = make_short4(f2bf(b.x*inv), f2bf(b.y*inv), f2bf(b.z*inv), f2bf(b.w*inv));
    *(short4*)(Fn + (size_t)row * D + lane * 4)       = o0;
    *(short4*)(Fn + (size_t)row * D + 256 + lane * 4) = o1;
}

// Upper-triangular tiles only: C = Fn*Fn^T -> exp -> masked row sums.
// Off-diagonal tiles contribute row sums (tile-row bm) AND column sums
// (tile-row bn, by symmetry of sim and of the mask).
__global__ void cc_gemm(const short* __restrict__ Fn, const int* __restrict__ cl,
                        float* __restrict__ tot, float* __restrict__ pos) {
    __shared__ __align__(16) short As[TILE * BK];   // [row][k] 128x64 bf16
    __shared__ __align__(16) short Bs[TILE * BK];
    __shared__ int crow[TILE], ccol[TILE];

    const int tid  = threadIdx.x;
    const int wave = tid >> 6;
    const int lane = tid & 63;

    // decode upper-triangle block index -> (bm, bn), bm <= bn
    int rem = blockIdx.x, bm = 0;
    while (rem >= NTB - bm) { rem -= NTB - bm; ++bm; }
    const int bn = bm + rem;
    const bool diag = (bm == bn);

    if (tid < TILE)            crow[tid]        = cl[bm * TILE + tid];
    else                       ccol[tid - TILE] = cl[bn * TILE + (tid - TILE)];

    const int wr = wave >> 1, wc = wave & 1;    // 2x2 wave grid, 64x64 each

    f32x4 acc[4][4];
    #pragma unroll
    for (int t = 0; t < 4; ++t)
        #pragma unroll
        for (int u = 0; u < 4; ++u) acc[t][u] = (f32x4)(0.0f);

    const int lrow = lane >> 3;          // 0..7   (row within 8-row chunk)
    const int lcol = (lane & 7) * 8;     // bf16 col offset, 16B per lane

    for (int kc = 0; kc < D / BK; ++kc) {
        __syncthreads();                 // LDS free (also covers crow/ccol on kc=0)
        #pragma unroll
        for (int i = 0; i < 4; ++i) {
            const int rb = i * 32 + wave * 8;            // wave-uniform row base
            const short* ga = Fn + (size_t)(bm * TILE + rb + lrow) * D + kc * BK + lcol;
            gload_lds16(ga, &As[rb * BK]);
            const short* gb = Fn + (size_t)(bn * TILE + rb + lrow) * D + kc * BK + lcol;
            gload_lds16(gb, &Bs[rb * BK]);
        }
        __syncthreads();                 // compiler drains vmcnt before barrier
        #pragma unroll
        for (int ks = 0; ks < 2; ++ks) {
            const int ko = ks * 32 + (lane >> 4) * 8;    // k = quad*8 + j
            bf16x8 af[4], bfr[4];
            #pragma unroll
            for (int t = 0; t < 4; ++t)
                af[t] = *(const bf16x8*)&As[(wr * 64 + t * 16 + (lane & 15)) * BK + ko];
            #pragma unroll
            for (int u = 0; u < 4; ++u)
                bfr[u] = *(const bf16x8*)&Bs[(wc * 64 + u * 16 + (lane & 15)) * BK + ko];
            #pragma unroll
            for (int t = 0; t < 4; ++t)
                #pragma unroll
                for (int u = 0; u < 4; ++u)
                    acc[t][u] = __builtin_amdgcn_mfma_f32_16x16x32_bf16(af[t], bfr[u], acc[t][u], 0, 0, 0);
        }
    }

    // epilogue: e = exp(sim/T) = exp2(dot * 10*log2(e)); C layout col=lane&15, row=q*4+reg
    const float SC = 14.426950408889634f;
    const int q   = lane >> 4;
    const int n15 = lane & 15;
    int cc[4];
    #pragma unroll
    for (int u = 0; u < 4; ++u) cc[u] = ccol[wc * 64 + u * 16 + n15];

    float ce[4] = {0.f, 0.f, 0.f, 0.f};   // per-column (lane-local) e sums
    float cp[4] = {0.f, 0.f, 0.f, 0.f};

    #pragma unroll
    for (int t = 0; t < 4; ++t) {
        #pragma unroll
        for (int r = 0; r < 4; ++r) {
            const int lr  = wr * 64 + t * 16 + q * 4 + r;   // local row
            const int myc = crow[lr];
            float te = 0.0f, tp = 0.0f;
            #pragma unroll
            for (int u = 0; u < 4; ++u) {
                const float e = exp2f(acc[t][u][r] * SC);
                const float ep = (cc[u] == myc) ? e : 0.0f;
                te += e;  tp += ep;
                ce[u] += e;  cp[u] += ep;
            }
            #pragma unroll
            for (int m = 1; m < 16; m <<= 1) {   // reduce across 16 cols
                te += __shfl_xor(te, m, 64);
                tp += __shfl_xor(tp, m, 64);
            }
            if (n15 == 0) {
                const int grow = bm * TILE + lr;
                atomicAdd(&tot[grow], te);
                atomicAdd(&pos[grow], tp);
            }
        }
    }

    if (!diag) {
        // column sums -> rows of tile bn. Column is fixed per lane (n15);
        // values spread across q only -> 2 butterfly stages.
        #pragma unroll
        for (int u = 0; u < 4; ++u) {
            float e = ce[u], p = cp[u];
            e += __shfl_xor(e, 16, 64);  p += __shfl_xor(p, 16, 64);
            e += __shfl_xor(e, 32, 64);  p += __shfl_xor(p, 32, 64);
            if (lane < 16) {
                const int grow = bn * TILE + wc * 64 + u * 16 + n15;
                atomicAdd(&tot[grow], e);
                atomicAdd(&pos[grow], p);
            }
        }
    }
}

// 32 blocks x 256 threads: one row per thread, block-reduce, atomic into out
__global__ void cc_finalize(const float* __restrict__ tot, const float* __restrict__ pos,
                            float* __restrict__ out) {
    __shared__ float red[4];
    const int i = blockIdx.x * 256 + threadIdx.x;
    float s = __logf(tot[i] + 1e-8f) - __logf(pos[i]);
    #pragma unroll
    for (int m = 32; m; m >>= 1) s += __shfl_xor(s, m, 64);
    const int wave = threadIdx.x >> 6, lane = threadIdx.x & 63;
    if (lane == 0) red[wave] = s;
    __syncthreads();
    if (threadIdx.x == 0) atomicAdd(out, red[0] + red[1] + red[2] + red[3]);
}

extern "C" void kernel_launch(void* const* d_in, const int* in_sizes, int n_in,
                              void* d_out, int out_size, void* d_ws, size_t ws_size,
                              hipStream_t stream) {
    const float* F  = (const float*)d_in[0];
    const int*   cl = (const int*)d_in[1];
    float* out = (float*)d_out;

    short* Fn  = (short*)d_ws;                                   // 8192*512 bf16 = 8 MB
    float* tot = (float*)((char*)d_ws + (size_t)N * D * 2);      // 32 KB
    float* pos = tot + N;                                        // 32 KB

    hipMemsetAsync(tot, 0, 2 * N * sizeof(float), stream);
    hipMemsetAsync(out, 0, sizeof(float), stream);
    cc_normalize<<<N / 4, 256, 0, stream>>>(F, Fn);
    cc_gemm<<<NTB * (NTB + 1) / 2, 256, 0, stream>>>(Fn, cl, tot, pos);
    cc_finalize<<<N / 256, 256, 0, stream>>>(tot, pos, out);
}